// Round 6
// baseline (113.595 us; speedup 1.0000x reference)
//
#include <hip/hip_runtime.h>

#define Bn   4
#define Nn   1024
#define Mn   100
#define NB   25
#define FEAT 50
#define PIc  3.1415926f
#define RSTEP (5.5f / 24.0f)
#define INVSTEP (24.0f / 5.5f)
#define RCUT 2.75f

#define ATB  16
#define NATOMS (Bn * Nn)
#define ORDER_LEN (NATOMS + ATB)        // 4112
#define MLP_BLOCKS (ORDER_LEN / ATB)    // 257
#define WMAT_USH 16384                  // one 128x128 bf16 matrix

#define GPB  32
#define CPG  32
#define FTHREADS 512

typedef __attribute__((ext_vector_type(8))) short bf16x8;
typedef __attribute__((ext_vector_type(4))) float f32x4;

union U16x8 { unsigned short u[8]; bf16x8 v; uint4 q; };

__device__ __forceinline__ unsigned short f2bh(float x) {
    union { float f; unsigned u; } v; v.f = x;
    unsigned r = v.u + 0x7fffu + ((v.u >> 16) & 1u);
    return (unsigned short)(r >> 16);
}
__device__ __forceinline__ float fast_tanh(float x) {
    float ax = fabsf(x);
    float t  = __expf(-2.0f * ax);
    float r  = (1.0f - t) * __builtin_amdgcn_rcpf(1.0f + t);
    return copysignf(r, x);
}

// ------------------------------------------------- prep: sort+weights+feat --
__global__ __launch_bounds__(256) void prep_kernel(
    const int* __restrict__ itype, const int* __restrict__ nlist,
    const float* __restrict__ dR,
    const float* __restrict__ W0, const float* __restrict__ W1,
    const float* __restrict__ W2,
    int* __restrict__ order, unsigned short* __restrict__ wsu,
    float* __restrict__ featp)
{
    const int t = threadIdx.x;
    if (blockIdx.x == 0) {
        // type partition: type-0 ids, pad to 16 with -1, type-1 ids, tail -1
        __shared__ int scan[256];
        for (int i = t; i < ORDER_LEN; i += 256) order[i] = -1;
        int tyv[16]; int c0 = 0;
        #pragma unroll
        for (int k = 0; k < 16; ++k) {
            int tt = (itype[t * 16 + k] == 8) ? 1 : 0;
            tyv[k] = tt; c0 += 1 - tt;
        }
        scan[t] = c0;
        __syncthreads();
        for (int off = 1; off < 256; off <<= 1) {
            int v = scan[t];
            int add = (t >= off) ? scan[t - off] : 0;
            __syncthreads();
            scan[t] = v + add;
            __syncthreads();
        }
        int total0 = scan[255];
        int ex0 = scan[t] - c0;
        int ex1 = 16 * t - ex0;
        int pad0 = (total0 + 15) & ~15;
        int p0 = ex0, p1 = pad0 + ex1;
        #pragma unroll
        for (int k = 0; k < 16; ++k) {
            int idx = t * 16 + k;
            if (tyv[k] == 0) order[p0++] = idx; else order[p1++] = idx;
        }
        return;
    }
    if (blockIdx.x <= 768) {
        // bf16 weight repack: [ty][mat][row][col], mats: WT0,WT1,WT2,WRM2,WRM1,WRM0
        int idx = (blockIdx.x - 1) * 256 + t;      // < 196608
        int ty = idx / 98304;
        int r  = idx - ty * 98304;
        int mat = r >> 14;
        int e = r & 16383;
        int row = e >> 7, col = e & 127;
        float v = 0.0f;
        if (mat == 0)      { if (col < 50  && row < 100) v = W0[ty * 5000  + col * 100 + row]; }
        else if (mat == 1) { if (col < 100 && row < 100) v = W1[ty * 10000 + col * 100 + row]; }
        else if (mat == 2) { if (col < 100 && row < 100) v = W2[ty * 10000 + col * 100 + row]; }
        else if (mat == 3) { if (row < 100 && col < 100) v = W2[ty * 10000 + row * 100 + col]; }
        else if (mat == 4) { if (row < 100 && col < 100) v = W1[ty * 10000 + row * 100 + col]; }
        else               { if (row < 50  && col < 100) v = W0[ty * 5000  + row * 100 + col]; }
        wsu[idx] = f2bh(v);
        return;
    }
    // feat: one block per atom; 100 pair-threads, LDS-atomic bell accumulation
    const int atom = blockIdx.x - 769;
    const int b = atom >> 10;
    __shared__ float sacc[FEAT];
    if (t < FEAT) sacc[t] = 0.0f;
    __syncthreads();
    if (t < Mn) {
        float4 qv = ((const float4*)dR)[(size_t)atom * Mn + t];
        int v = nlist[(size_t)atom * Mn + t];
        if (v > 0) {
            float r = qv.x;
            if (r > 0.0f && r < 6.0f) {
                int tt = (itype[b * Nn + v - 1] == 8) ? 1 : 0;
                float cw = 0.5f * __cosf(PIc * r) + 0.5f;
                int k0 = (int)ceilf((r - 0.5f - RCUT) * INVSTEP);
                int k1 = (int)floorf((r - 0.5f + RCUT) * INVSTEP);
                k0 = max(k0, 0); k1 = min(k1, 24);
                for (int k = k0; k <= k1; ++k) {
                    float d = r - (0.5f + k * RSTEP);
                    atomicAdd(&sacc[tt * NB + k], __expf(-d * d) * cw);
                }
            }
        }
    }
    __syncthreads();
    if (t < 64) featp[(size_t)atom * 64 + t] = (t < FEAT) ? sacc[t] : 0.0f;
}

// ----------------------------------------------------------------- mlp ----
// 256 thr = 4 waves, 16 type-pure atoms. Per phase: one 128x128 bf16 weight
// matrix in XOR-swizzled LDS; next matrix reg-prefetched during GEMM.
#define ISSUE_W(MAT)                                                          \
    { const uint4* srcp = (const uint4*)(wbase + (MAT) * WMAT_USH);           \
      _Pragma("unroll")                                                       \
      for (int i = 0; i < 8; ++i) wreg[i] = srcp[(srow + 16 * i) * 16 + sg]; }

#define WRITE_W()                                                             \
    { _Pragma("unroll")                                                       \
      for (int i = 0; i < 8; ++i)                                             \
          *(uint4*)&wlds[((srow + 16 * i) << 7) | (sperm << 3)] = wreg[i]; }

#define GEMM2(BUF, NKT)                                                       \
    { _Pragma("unroll")                                                       \
      for (int kt = 0; kt < (NKT); ++kt) {                                    \
        int gk = kt * 4 + q;                                                  \
        bf16x8 af = *(const bf16x8*)&aA[BUF][(c << 7) | ((gk ^ (c & 7)) << 3)]; \
        _Pragma("unroll")                                                     \
        for (int s2 = 0; s2 < 2; ++s2) {                                      \
            int jj = c + 16 * (2 * w + s2);                                   \
            bf16x8 bf = *(const bf16x8*)&wlds[(jj << 7) | ((gk ^ (c & 7)) << 3)]; \
            acc[s2] = __builtin_amdgcn_mfma_f32_16x16x32_bf16(af, bf, acc[s2], 0, 0, 0); \
        } } }

#define WRACT(BUF, J, A, X)                                                   \
    aA[BUF][((A) << 7) | ((((J) >> 3) ^ ((A) & 7)) << 3) | ((J) & 7)] = f2bh(X)

__global__ __launch_bounds__(256) void mlp_kernel(
    const float* __restrict__ featp, const int* __restrict__ itype,
    const int* __restrict__ order, const unsigned short* __restrict__ wsu,
    const float* __restrict__ B0, const float* __restrict__ B1,
    const float* __restrict__ B2, const float* __restrict__ W3,
    const float* __restrict__ B3,
    float* __restrict__ Ei, float* __restrict__ dE)
{
    const int t = threadIdx.x;
    const int w = t >> 6;
    const int lane = t & 63;
    const int c = lane & 15, q = lane >> 4;

    __shared__ unsigned short wlds[16384];      // 32KB
    __shared__ unsigned short aA[2][2048];      // 8KB
    __shared__ float fshf[16][52];
    __shared__ float dx1s[16][112];
    __shared__ float biasS[4][128];
    __shared__ float eip[4][16];
    __shared__ int aid[16];

    if (t < 16) aid[t] = order[blockIdx.x * ATB + t];
    __syncthreads();
    int first = -1;
    #pragma unroll
    for (int a = 0; a < ATB; ++a) { int v = aid[a]; if (first < 0 && v >= 0) first = v; }
    if (first < 0) return;
    const int ty = (itype[first] == 8) ? 1 : 0;
    const unsigned short* wbase = wsu + (size_t)ty * 6 * WMAT_USH;

    const int srow = t >> 4, sg = t & 15;
    const int sperm = sg ^ (srow & 7);
    uint4 wreg[8];

    // prologue: WT0 + feats + biases
    ISSUE_W(0);
    {
        int v = aid[srow];
        float4 fa = {0,0,0,0}, fb = {0,0,0,0};
        if (v >= 0) {
            const float4* fp = (const float4*)(featp + (size_t)v * 64 + sg * 8);
            fa = fp[0]; fb = fp[1];
        }
        U16x8 pk;
        pk.u[0]=f2bh(fa.x); pk.u[1]=f2bh(fa.y); pk.u[2]=f2bh(fa.z); pk.u[3]=f2bh(fa.w);
        pk.u[4]=f2bh(fb.x); pk.u[5]=f2bh(fb.y); pk.u[6]=f2bh(fb.z); pk.u[7]=f2bh(fb.w);
        *(uint4*)&aA[0][(srow << 7) | (sperm << 3)] = pk.q;
        int cbase = sg * 8;
        if (cbase < 52) {
            float vals[8] = {fa.x,fa.y,fa.z,fa.w,fb.x,fb.y,fb.z,fb.w};
            #pragma unroll
            for (int j7 = 0; j7 < 8; ++j7)
                if (cbase + j7 < 52) fshf[srow][cbase + j7] = vals[j7];
        }
    }
    for (int idx = t; idx < 512; idx += 256) {
        int row = idx >> 7, col = idx & 127;
        const float* s = (row == 0) ? B0 : (row == 1) ? B1 : (row == 2) ? B2 : W3;
        biasS[row][col] = (col < 100) ? s[ty * 100 + col] : 0.0f;
    }
    WRITE_W();
    __syncthreads();

    f32x4 acc[2];
    float xr[2][4], h0r[2][4], h1r[2][4], h2r[2][4], dxr[2][4];

    // ---------------- P0: L0 (wlds=WT0, A=aA0 feat, out aA1) ----------------
    ISSUE_W(1);
    acc[0] = (f32x4){0,0,0,0}; acc[1] = acc[0];
    GEMM2(0, 2);
    #pragma unroll
    for (int s = 0; s < 2; ++s) {
        int j = c + 16 * (2 * w + s);
        float bj = biasS[0][j];
        #pragma unroll
        for (int r = 0; r < 4; ++r) {
            int a = q * 4 + r;
            float z = acc[s][r] + bj;
            float h = 0.f, x = 0.f;
            if (j < 100) { h = fast_tanh(z); x = h + fshf[a][(j < 50) ? j : j - 50]; }
            h0r[s][r] = h; xr[s][r] = x;
            WRACT(1, j, a, x);
        }
    }
    __syncthreads();
    WRITE_W();
    __syncthreads();

    // ---------------- P1: L1 (wlds=WT1, A=aA1, out aA0) ----------------
    ISSUE_W(2);
    acc[0] = (f32x4){0,0,0,0}; acc[1] = acc[0];
    GEMM2(1, 4);
    #pragma unroll
    for (int s = 0; s < 2; ++s) {
        int j = c + 16 * (2 * w + s);
        float bj = biasS[1][j];
        #pragma unroll
        for (int r = 0; r < 4; ++r) {
            int a = q * 4 + r;
            float z = acc[s][r] + bj;
            float h = (j < 100) ? fast_tanh(z) : 0.f;
            float x = (j < 100) ? (h + xr[s][r]) : 0.f;
            h1r[s][r] = h; xr[s][r] = x;
            WRACT(0, j, a, x);
        }
    }
    __syncthreads();
    WRITE_W();
    __syncthreads();

    // ---------------- P2: L2 (wlds=WT2, A=aA0) ----------------
    ISSUE_W(3);
    acc[0] = (f32x4){0,0,0,0}; acc[1] = acc[0];
    GEMM2(0, 4);
    #pragma unroll
    for (int s = 0; s < 2; ++s) {
        int j = c + 16 * (2 * w + s);
        float bj = biasS[2][j];
        #pragma unroll
        for (int r = 0; r < 4; ++r) {
            float z = acc[s][r] + bj;
            float h = (j < 100) ? fast_tanh(z) : 0.f;
            h2r[s][r] = h;
            xr[s][r] = (j < 100) ? (h + xr[s][r]) : 0.f;   // x3
        }
    }
    // Ei partials + dz2 -> aA1
    {
        float p4[4] = {0,0,0,0};
        #pragma unroll
        for (int s = 0; s < 2; ++s) {
            int j = c + 16 * (2 * w + s);
            float wv = biasS[3][j];
            #pragma unroll
            for (int r = 0; r < 4; ++r) p4[r] += xr[s][r] * wv;
        }
        #pragma unroll
        for (int off = 1; off < 16; off <<= 1) {
            #pragma unroll
            for (int r = 0; r < 4; ++r) p4[r] += __shfl_xor(p4[r], off);
        }
        if (c == 0) {
            #pragma unroll
            for (int r = 0; r < 4; ++r) eip[w][q * 4 + r] = p4[r];
        }
        #pragma unroll
        for (int s = 0; s < 2; ++s) {
            int j = c + 16 * (2 * w + s);
            float w3j = biasS[3][j];
            #pragma unroll
            for (int r = 0; r < 4; ++r) {
                int a = q * 4 + r;
                float d = w3j * (1.0f - h2r[s][r] * h2r[s][r]);
                WRACT(1, j, a, d);
            }
        }
    }
    __syncthreads();
    WRITE_W();
    __syncthreads();
    if (t < 16) {
        int v = aid[t];
        if (v >= 0) Ei[v] = eip[0][t] + eip[1][t] + eip[2][t] + eip[3][t] + B3[ty];
    }

    // ---------------- P3: bwd2 (wlds=WRM2, A=aA1 dz2, out aA0 dz1) ----------
    ISSUE_W(4);
    acc[0] = (f32x4){0,0,0,0}; acc[1] = acc[0];
    GEMM2(1, 4);
    #pragma unroll
    for (int s = 0; s < 2; ++s) {
        int i = c + 16 * (2 * w + s);
        float w3i = biasS[3][i];
        #pragma unroll
        for (int r = 0; r < 4; ++r) {
            int a = q * 4 + r;
            float dx2 = acc[s][r] + w3i;
            dxr[s][r] = dx2;
            float d = dx2 * (1.0f - h1r[s][r] * h1r[s][r]);   // dz1
            WRACT(0, i, a, d);
        }
    }
    __syncthreads();
    WRITE_W();
    __syncthreads();

    // ---------------- P4: bwd1 (wlds=WRM1, A=aA0 dz1, out aA1 dz0) ----------
    ISSUE_W(5);
    acc[0] = (f32x4){0,0,0,0}; acc[1] = acc[0];
    GEMM2(0, 4);
    #pragma unroll
    for (int s = 0; s < 2; ++s) {
        int i = c + 16 * (2 * w + s);
        #pragma unroll
        for (int r = 0; r < 4; ++r) {
            int a = q * 4 + r;
            float dx1 = dxr[s][r] + acc[s][r];
            if (i < 112) dx1s[a][i] = dx1;
            float d = dx1 * (1.0f - h0r[s][r] * h0r[s][r]);   // dz0
            WRACT(1, i, a, d);
        }
    }
    __syncthreads();
    WRITE_W();
    __syncthreads();

    // ---------------- P5: bwd0 (wlds=WRM0, A=aA1 dz0) ----------
    {
        f32x4 a2 = (f32x4){0,0,0,0};
        #pragma unroll
        for (int kt = 0; kt < 4; ++kt) {
            int gk = kt * 4 + q;
            bf16x8 af = *(const bf16x8*)&aA[1][(c << 7) | ((gk ^ (c & 7)) << 3)];
            int jj = c + 16 * w;
            bf16x8 bf = *(const bf16x8*)&wlds[(jj << 7) | ((gk ^ (c & 7)) << 3)];
            a2 = __builtin_amdgcn_mfma_f32_16x16x32_bf16(af, bf, a2, 0, 0, 0);
        }
        int f = c + 16 * w;
        if (f < 50) {
            #pragma unroll
            for (int r = 0; r < 4; ++r) {
                int a = q * 4 + r;
                int v = aid[a];
                if (v >= 0) dE[(size_t)v * FEAT + f] = a2[r] + dx1s[a][f] + dx1s[a][f + 50];
            }
        }
    }
}

// --------------------------------------------------------------- force ----
__global__ __launch_bounds__(FTHREADS) void force_kernel(
    const int* __restrict__ itype, const int* __restrict__ nlist,
    const float* __restrict__ dR, const float* __restrict__ dE,
    float* __restrict__ partial)
{
    const int blk = blockIdx.x;
    const int b = blk / GPB;
    const int g = blk - b * GPB;
    const int t = threadIdx.x;

    __shared__ float acc[(Nn + 1) * 3];
    __shared__ float desh[CPG][FEAT];

    for (int idx = t; idx < (Nn + 1) * 3; idx += FTHREADS) acc[idx] = 0.0f;
    for (int idx = t; idx < CPG * FEAT; idx += FTHREADS)
        ((float*)desh)[idx] = dE[((size_t)(b * Nn) + g * CPG) * FEAT + idx];
    __syncthreads();

    for (int p = t; p < CPG * Mn; p += FTHREADS) {
        int cc = p / Mn, m = p - cc * Mn;
        int n = g * CPG + cc;
        size_t pair = (size_t)(b * Nn + n) * Mn + m;
        float4 qv = ((const float4*)dR)[pair];
        int v = nlist[pair];
        if (v > 0) {
            float r = qv.x;
            if (r > 0.0f && r < 6.0f) {
                int tt = (itype[b * Nn + v - 1] == 8) ? 1 : 0;
                float cw  = 0.5f * __cosf(PIc * r) + 0.5f;
                float dcw = -0.5f * PIc * __sinf(PIc * r);
                int k0 = (int)ceilf((r - 0.5f - RCUT) * INVSTEP);
                int k1 = (int)floorf((r - 0.5f + RCUT) * INVSTEP);
                k0 = max(k0, 0); k1 = min(k1, 24);
                float s = 0.0f;
                const float* de = &desh[cc][tt * NB];
                for (int k = k0; k <= k1; ++k) {
                    float d = r - (0.5f + k * RSTEP);
                    float e = __expf(-d * d);
                    s += de[k] * e * __builtin_fmaf(-2.0f * cw, d, dcw);
                }
                float inv = 1.0f / r;
                float fx = s * qv.y * inv, fy = s * qv.z * inv, fz = s * qv.w * inv;
                atomicAdd(&acc[v * 3 + 0], fx);
                atomicAdd(&acc[v * 3 + 1], fy);
                atomicAdd(&acc[v * 3 + 2], fz);
                atomicAdd(&acc[(n + 1) * 3 + 0], -fx);
                atomicAdd(&acc[(n + 1) * 3 + 1], -fy);
                atomicAdd(&acc[(n + 1) * 3 + 2], -fz);
            }
        }
    }
    __syncthreads();

    float* pout = partial + (size_t)blk * ((Nn + 1) * 3);
    for (int idx = t; idx < (Nn + 1) * 3; idx += FTHREADS) pout[idx] = acc[idx];
}

// ----------------------------------------------------- freduce (+etot) ----
__global__ __launch_bounds__(256) void freduce_kernel(
    const float* __restrict__ partial, const float* __restrict__ Ei,
    float* __restrict__ Force, float* __restrict__ Etot)
{
    if (blockIdx.x == 48) {   // etot
        const int t = threadIdx.x;
        __shared__ float red[256];
        for (int b = 0; b < Bn; ++b) {
            float s = 0.0f;
            for (int i = t; i < Nn; i += 256) s += Ei[b * Nn + i];
            red[t] = s;
            __syncthreads();
            for (int st = 128; st > 0; st >>= 1) {
                if (t < st) red[t] += red[t + st];
                __syncthreads();
            }
            if (t == 0) Etot[b] = red[0];
            __syncthreads();
        }
        return;
    }
    int idx = blockIdx.x * 256 + threadIdx.x;
    if (idx >= Bn * Nn * 3) return;
    int b = idx / (Nn * 3);
    int r = idx - b * (Nn * 3);
    int i = r / 3, ch = r - i * 3;
    float s = 0.0f;
    for (int g = 0; g < GPB; ++g)
        s += partial[((size_t)(b * GPB + g)) * ((Nn + 1) * 3) + (size_t)(i + 1) * 3 + ch];
    Force[idx] = s;
}

// -------------------------------------------------------------- launch ----
extern "C" void kernel_launch(void* const* d_in, const int* in_sizes, int n_in,
                              void* d_out, int out_size, void* d_ws, size_t ws_size,
                              hipStream_t stream)
{
    const int*   itype = (const int*)d_in[0];
    const int*   nlist = (const int*)d_in[1];
    const float* dR    = (const float*)d_in[2];
    const float* W0 = (const float*)d_in[3];  const float* B0 = (const float*)d_in[4];
    const float* W1 = (const float*)d_in[5];  const float* B1 = (const float*)d_in[6];
    const float* W2 = (const float*)d_in[7];  const float* B2 = (const float*)d_in[8];
    const float* W3 = (const float*)d_in[9];  const float* B3 = (const float*)d_in[10];

    float* out   = (float*)d_out;
    float* Etot  = out;                    // [B,1]
    float* Ei    = out + Bn;               // [B,N,1]
    float* Force = out + Bn + Bn * Nn;     // [B,N,3]

    float* featp   = (float*)d_ws;                              // NATOMS*64
    float* dEp     = featp + (size_t)NATOMS * 64;               // NATOMS*50
    float* partial = dEp + (size_t)NATOMS * FEAT;               // Bn*GPB*(Nn+1)*3
    int*   order   = (int*)(partial + (size_t)Bn * GPB * (Nn + 1) * 3);
    unsigned short* wsu = (unsigned short*)(order + ORDER_LEN); // 196608 ushort

    prep_kernel   <<<1 + 768 + NATOMS, 256, 0, stream>>>(itype, nlist, dR,
                                                         W0, W1, W2, order, wsu, featp);
    mlp_kernel    <<<MLP_BLOCKS, 256, 0, stream>>>(featp, itype, order, wsu,
                                                   B0, B1, B2, W3, B3, Ei, dEp);
    force_kernel  <<<Bn * GPB, FTHREADS, 0, stream>>>(itype, nlist, dR, dEp, partial);
    freduce_kernel<<<49, 256, 0, stream>>>(partial, Ei, Force, Etot);
}